// Round 1
// baseline (3611.853 us; speedup 1.0000x reference)
//
#include <hip/hip_runtime.h>
#include <math.h>

#define BT 65536      // batch rows
#define NIN 1024      // input dim (reduction)
#define KK 1024       // codes (logit cols)
#define EE 256        // embedding dim
#define MT 32         // rows per block
#define KB 16         // reduction chunk staged per iteration
#define WSP 1028      // ws row stride: 1024+4 pad -> 4*WSP%32==16 -> 2-way (free) transpose writes
#define XSP 16        // xs row stride (natural layout, = KB)
#define LOGK 6.9314718055994531f

// Fused kernel: logits GEMM + gumbel + softmax stats + argmax + codebook gather
// + avg_p partial accumulation.
//
// Block: 256 threads = 4 waves. Wave w owns rows 8*w..8*w+7 and ALL 1024 cols.
// Thread tile: 8 rows x 16 cols (lg = 128 VGPRs). Lane l covers cols
// {p*256 + 4l + j : p<4, j<4}.
// B-reads: ds_read_b128 at ws[n][p*256+4l] -> 64 lanes contiguous 1024B
// (conflict-free identity pattern). A-reads: wave-uniform broadcast b128 from
// natural-layout xs (broadcasts never conflict). 128 FMA per 6 LDS reads per
// n-step (vs 32 per 3 before) -> LDS pipe no longer the bottleneck.
__global__ __launch_bounds__(256, 2)
void vq_main(const float* __restrict__ x, const float* __restrict__ gum,
             const float* __restrict__ W, const float* __restrict__ bias,
             const float* __restrict__ cbk, float* __restrict__ out,
             float* __restrict__ gsum) {
    __shared__ __align__(16) float smem[MT * XSP + KB * WSP];  // 512 + 16448 floats = 67.8 KB
    float* xs = smem;             // [row][n]  32 x 16 (natural)
    float* ws = smem + MT * XSP;  // [n][col]  16 x 1028 (transposed, padded)

    const int tid = threadIdx.x;
    const int l   = tid & 63;     // lane in wave
    const int wid = tid >> 6;     // wave 0..3 -> rows 8*wid..8*wid+7
    const int row0 = blockIdx.x * MT;

    float lg[8][16];              // [row r][t = p*4+j], col = p*256 + 4*l + j
    #pragma unroll
    for (int r = 0; r < 8; ++r)
        #pragma unroll
        for (int t = 0; t < 16; ++t) lg[r][t] = 0.f;

    // staging indices
    const int xr = tid >> 2;          // x row (threads 0..127 stage x)
    const int xf = (tid & 3) << 2;    // x n-offset 0,4,8,12
    const int wc0 = tid >> 2;         // W col base (+64 per lw iter)
    const int wf  = (tid & 3) << 2;   // W n-offset 0,4,8,12

    for (int kc = 0; kc < NIN / KB; ++kc) {
        const int n0 = kc * KB;
        // stage x tile (32 rows x 16 n), natural layout: contiguous b128 writes
        if (tid < 128) {
            const float4 xv = *(const float4*)(x + (size_t)(row0 + xr) * NIN + n0 + xf);
            *(float4*)(xs + xr * XSP + xf) = xv;
        }
        // stage W tile (1024 cols x 16 n) transposed into ws[n][col]
        // write bank = (16f + 4j + c) % 32 -> 2-way alias only (free)
        #pragma unroll
        for (int lw = 0; lw < 16; ++lw) {
            const int c = wc0 + (lw << 6);
            const float4 wv = *(const float4*)(W + (size_t)c * NIN + n0 + wf);
            ws[(wf + 0) * WSP + c] = wv.x;
            ws[(wf + 1) * WSP + c] = wv.y;
            ws[(wf + 2) * WSP + c] = wv.z;
            ws[(wf + 3) * WSP + c] = wv.w;
        }
        __syncthreads();
        #pragma unroll
        for (int nb = 0; nb < 4; ++nb) {
            // a-fragments: 8 rows x 4 n, wave-uniform broadcast reads
            float a4[8][4];
            #pragma unroll
            for (int r = 0; r < 8; ++r) {
                const float4 av = *(const float4*)(xs + (8 * wid + r) * XSP + (nb << 2));
                a4[r][0] = av.x; a4[r][1] = av.y; a4[r][2] = av.z; a4[r][3] = av.w;
            }
            #pragma unroll
            for (int m = 0; m < 4; ++m) {
                const int n = (nb << 2) + m;
                // b-fragments: 4 panes x 4 cols, identity-contiguous b128 reads
                float bf[4][4];
                #pragma unroll
                for (int p = 0; p < 4; ++p) {
                    const float4 bv = *(const float4*)(ws + n * WSP + (p << 8) + (l << 2));
                    bf[p][0] = bv.x; bf[p][1] = bv.y; bf[p][2] = bv.z; bf[p][3] = bv.w;
                }
                #pragma unroll
                for (int r = 0; r < 8; ++r)
                    #pragma unroll
                    for (int p = 0; p < 4; ++p)
                        #pragma unroll
                        for (int j = 0; j < 4; ++j)
                            lg[r][(p << 2) + j] = fmaf(a4[r][m], bf[p][j], lg[r][(p << 2) + j]);
            }
        }
        __syncthreads();
    }

    // add bias + gumbel (tau = 1.0); loads are lane-contiguous float4
    float bb[16];
    #pragma unroll
    for (int p = 0; p < 4; ++p) {
        const float4 b4 = *(const float4*)(bias + (p << 8) + (l << 2));
        bb[(p << 2) + 0] = b4.x; bb[(p << 2) + 1] = b4.y;
        bb[(p << 2) + 2] = b4.z; bb[(p << 2) + 3] = b4.w;
    }
    #pragma unroll
    for (int r = 0; r < 8; ++r) {
        const int row = row0 + (wid << 3) + r;
        #pragma unroll
        for (int p = 0; p < 4; ++p) {
            const float4 g4 = *(const float4*)(gum + (size_t)row * KK + (p << 8) + (l << 2));
            lg[r][(p << 2) + 0] += bb[(p << 2) + 0] + g4.x;
            lg[r][(p << 2) + 1] += bb[(p << 2) + 1] + g4.y;
            lg[r][(p << 2) + 2] += bb[(p << 2) + 2] + g4.z;
            lg[r][(p << 2) + 3] += bb[(p << 2) + 3] + g4.w;
        }
    }

    // per-row: argmax (first-occurrence tie-break), softmax, z_q gather, m
    #pragma unroll
    for (int r = 0; r < 8; ++r) {
        float mv = -1e30f; int mi = 0;
        #pragma unroll
        for (int t = 0; t < 16; ++t) {          // t ascending == col ascending per lane
            const int c = ((t >> 2) << 8) + (l << 2) + (t & 3);
            if (lg[r][t] > mv) { mv = lg[r][t]; mi = c; }
        }
        #pragma unroll
        for (int off = 1; off < 64; off <<= 1) {  // full-wave reduction
            const float ov = __shfl_xor(mv, off);
            const int   oi = __shfl_xor(mi, off);
            if (ov > mv || (ov == mv && oi < mi)) { mv = ov; mi = oi; }
        }
        float s = 0.f;
        #pragma unroll
        for (int t = 0; t < 16; ++t) {
            const float e = __expf(lg[r][t] - mv);
            lg[r][t] = e;
            s += e;
        }
        #pragma unroll
        for (int off = 1; off < 64; off <<= 1) s += __shfl_xor(s, off);
        const float rinv = 1.f / s;
        #pragma unroll
        for (int t = 0; t < 16; ++t) lg[r][t] *= rinv;

        const int row = row0 + (wid << 3) + r;
        // z_q[row] = codebook[mi]  (forward value of straight-through = hard)
        const float4 cv = *(const float4*)(cbk + (size_t)mi * EE + (l << 2));
        *(float4*)(out + (size_t)row * EE + (l << 2)) = cv;
        if (l == 0) out[(size_t)BT * EE + row] = (float)mi;
    }

    // avg_p partials: sum p over this block's 32 rows per column, then one
    // global atomicAdd per column per block.
    #pragma unroll
    for (int t = 0; t < 16; ++t)
        #pragma unroll
        for (int r = 1; r < 8; ++r) lg[0][t] += lg[r][t];
    __syncthreads();                 // done with GEMM staging; reuse smem
    float* aggp = smem;
    for (int q = tid; q < KK; q += 256) aggp[q] = 0.f;
    __syncthreads();
    #pragma unroll
    for (int t = 0; t < 16; ++t) {
        const int c = ((t >> 2) << 8) + (l << 2) + (t & 3);
        atomicAdd(&aggp[c], lg[0][t]);   // 4-way (one per wave) LDS contention
    }
    __syncthreads();
    for (int q = tid; q < KK; q += 256) atomicAdd(&gsum[q], aggp[q]);
}

// Finalize: diversity = sum avg_p * (log(clip(avg_p,1e-9)) + log K); also the
// trailing zero scalar.
__global__ void vq_fin(const float* __restrict__ gsum, float* __restrict__ out) {
    __shared__ float red[4];
    const int tid = threadIdx.x;
    float local = 0.f;
    for (int q = tid; q < KK; q += 256) {
        const float a = gsum[q] * (1.0f / (float)BT);
        local += a * (logf(fmaxf(a, 1e-9f)) + LOGK);
    }
    #pragma unroll
    for (int off = 1; off < 64; off <<= 1) local += __shfl_xor(local, off);
    if ((tid & 63) == 0) red[tid >> 6] = local;
    __syncthreads();
    if (tid == 0) {
        out[(size_t)BT * EE + BT]     = red[0] + red[1] + red[2] + red[3];
        out[(size_t)BT * EE + BT + 1] = 0.f;
    }
}

extern "C" void kernel_launch(void* const* d_in, const int* in_sizes, int n_in,
                              void* d_out, int out_size, void* d_ws, size_t ws_size,
                              hipStream_t stream) {
    const float* x   = (const float*)d_in[0];
    const float* g   = (const float*)d_in[1];
    const float* W   = (const float*)d_in[2];
    const float* b   = (const float*)d_in[3];
    const float* cbk = (const float*)d_in[4];
    float* out  = (float*)d_out;
    float* gsum = (float*)d_ws;

    hipMemsetAsync(gsum, 0, KK * sizeof(float), stream);
    vq_main<<<BT / MT, 256, 0, stream>>>(x, g, W, b, cbk, out, gsum);
    vq_fin<<<1, 256, 0, stream>>>(gsum, out);
}

// Round 2
// 2500.324 us; speedup vs baseline: 1.4446x; 1.4446x over previous
//
#include <hip/hip_runtime.h>
#include <math.h>

#define BT 65536      // batch rows
#define NIN 1024      // input dim (reduction)
#define KK 1024       // codes (logit cols)
#define EE 256        // embedding dim
#define MT 32         // rows per block
#define KB 16         // reduction chunk staged per iteration
#define WSP 1028      // ws row stride: 4*WSP%32==16 -> transpose writes 2-way (free)
#define XSP 16        // xs row stride (natural layout, = KB)
#define LOGK 6.9314718055994531f

// Fused kernel: logits GEMM + gumbel + softmax stats + argmax + codebook gather
// + avg_p partial accumulation.
//
// Block: 512 threads = 8 waves. Wave w: row group g=w>>1 (rows 8g..8g+7),
// col half h=w&1 (cols 512h..512h+511). Thread tile: 8 rows x 8 cols
// (lg = 64 VGPRs; total live ~100 -> fits the 128-VGPR budget, no scratch).
// B-reads: ds_read_b128 at ws[n][512h + 256p + 4l] -> 64 lanes contiguous
// 1024B (conflict-free identity). A-reads: wave-uniform broadcast b64 from
// natural-layout xs (broadcasts never conflict).
// Row softmax spans 2 waves -> small LDS cross-half combine.
__global__ __launch_bounds__(512, 4)
void vq_main(const float* __restrict__ x, const float* __restrict__ gum,
             const float* __restrict__ W, const float* __restrict__ bias,
             const float* __restrict__ cbk, float* __restrict__ out,
             float* __restrict__ gsum) {
    __shared__ __align__(16) float smem[MT * XSP + KB * WSP];  // 512+16448 floats = 66.3 KB
    float* xs = smem;             // [row][n]  32 x 16 (natural)
    float* ws = smem + MT * XSP;  // [n][col]  16 x 1028 (transposed, padded)

    const int tid = threadIdx.x;
    const int l   = tid & 63;     // lane
    const int wid = tid >> 6;     // wave 0..7
    const int g   = wid >> 1;     // row group 0..3 -> rows 8g..8g+7
    const int h   = wid & 1;      // col half 0..1  -> cols 512h..512h+511
    const int row0 = blockIdx.x * MT;

    float lg[8][8];               // [row r][t = 4p+j], col = 512h + 256p + 4l + j
    #pragma unroll
    for (int r = 0; r < 8; ++r)
        #pragma unroll
        for (int t = 0; t < 8; ++t) lg[r][t] = 0.f;

    const int xr = tid >> 2;          // x stage: threads 0..127, row 0..31
    const int xf = (tid & 3) << 2;    // n-offset 0,4,8,12
    const int cb0 = (h << 9) + (l << 2);  // this lane's first col (p=0)

    for (int kc = 0; kc < NIN / KB; ++kc) {
        const int n0 = kc * KB;
        // stage x tile (32 rows x 16 n), natural layout: contiguous b128 writes
        if (tid < 128) {
            const float4 xv = *(const float4*)(x + (size_t)(row0 + xr) * NIN + n0 + xf);
            *(float4*)(xs + xr * XSP + xf) = xv;
        }
        // stage W tile (1024 cols x 16 n) transposed into ws[n][col]
        // write bank = (4nf+4k+c)%32 -> 2-way alias only (free per m136)
        #pragma unroll
        for (int i = 0; i < 8; ++i) {
            const int flat = tid + (i << 9);      // 0..4095
            const int c  = flat >> 2;             // 0..1023
            const int nf = (flat & 3) << 2;       // 0,4,8,12
            const float4 wv = *(const float4*)(W + (size_t)c * NIN + n0 + nf);
            ws[(nf + 0) * WSP + c] = wv.x;
            ws[(nf + 1) * WSP + c] = wv.y;
            ws[(nf + 2) * WSP + c] = wv.z;
            ws[(nf + 3) * WSP + c] = wv.w;
        }
        __syncthreads();
        #pragma unroll
        for (int nb = 0; nb < KB / 2; ++nb) {
            // a-fragments: 8 rows x 2 n, wave-uniform broadcast b64 reads
            float a2[8][2];
            #pragma unroll
            for (int r = 0; r < 8; ++r) {
                const float2 av = *(const float2*)(xs + ((g << 3) + r) * XSP + (nb << 1));
                a2[r][0] = av.x; a2[r][1] = av.y;
            }
            #pragma unroll
            for (int m = 0; m < 2; ++m) {
                const int n = (nb << 1) + m;
                // b-fragments: 2 panes x 4 cols, identity-contiguous b128 reads
                const float4 b0 = *(const float4*)(ws + n * WSP + cb0);
                const float4 b1 = *(const float4*)(ws + n * WSP + cb0 + 256);
                const float bf[8] = {b0.x, b0.y, b0.z, b0.w, b1.x, b1.y, b1.z, b1.w};
                #pragma unroll
                for (int r = 0; r < 8; ++r)
                    #pragma unroll
                    for (int t = 0; t < 8; ++t)
                        lg[r][t] = fmaf(a2[r][m], bf[t], lg[r][t]);
            }
        }
        __syncthreads();
    }

    // add bias + gumbel (tau = 1.0); lane-contiguous float4 loads
    {
        const float4 bb0 = *(const float4*)(bias + cb0);
        const float4 bb1 = *(const float4*)(bias + cb0 + 256);
        #pragma unroll
        for (int r = 0; r < 8; ++r) {
            const int row = row0 + (g << 3) + r;
            const float4 g0 = *(const float4*)(gum + (size_t)row * KK + cb0);
            const float4 g1 = *(const float4*)(gum + (size_t)row * KK + cb0 + 256);
            lg[r][0] += bb0.x + g0.x;  lg[r][1] += bb0.y + g0.y;
            lg[r][2] += bb0.z + g0.z;  lg[r][3] += bb0.w + g0.w;
            lg[r][4] += bb1.x + g1.x;  lg[r][5] += bb1.y + g1.y;
            lg[r][6] += bb1.z + g1.z;  lg[r][7] += bb1.w + g1.w;
        }
    }

    // epilogue LDS scratch (disjoint regions; GEMM staging is dead after the
    // final barrier inside the kc loop)
    float* red  = smem;         // [32 rows][2 halves][2: mv, mi-bits] = 128 floats
    float* ssum = smem + 128;   // [32 rows][2 halves] = 64 floats
    float* aggp = smem + 256;   // [1024]

    // Phase A: per-wave (half-row) max/argmax -> LDS
    #pragma unroll
    for (int r = 0; r < 8; ++r) {
        float mv = -1e30f; int mi = 0;
        #pragma unroll
        for (int t = 0; t < 8; ++t) {          // t ascending == col ascending
            const int c = cb0 + ((t >> 2) << 8) + (t & 3);
            if (lg[r][t] > mv) { mv = lg[r][t]; mi = c; }
        }
        #pragma unroll
        for (int off = 1; off < 64; off <<= 1) {
            const float ov = __shfl_xor(mv, off);
            const int   oi = __shfl_xor(mi, off);
            if (ov > mv || (ov == mv && oi < mi)) { mv = ov; mi = oi; }
        }
        if (l == 0) {
            const int idx = (((g << 3) + r) << 2) + (h << 1);
            red[idx]     = mv;
            red[idx + 1] = __int_as_float(mi);
        }
    }
    __syncthreads();

    // Phase B: combine halves, exp + per-half sum -> LDS
    int MI[8];
    #pragma unroll
    for (int r = 0; r < 8; ++r) {
        const int idx = (((g << 3) + r) << 2);
        const float m0 = red[idx],     m1 = red[idx + 2];
        const int   i0 = __float_as_int(red[idx + 1]);
        const int   i1 = __float_as_int(red[idx + 3]);
        float MV; int Mi;
        if (m1 > m0 || (m1 == m0 && i1 < i0)) { MV = m1; Mi = i1; }
        else                                  { MV = m0; Mi = i0; }
        MI[r] = Mi;
        float s = 0.f;
        #pragma unroll
        for (int t = 0; t < 8; ++t) {
            const float e = __expf(lg[r][t] - MV);
            lg[r][t] = e;
            s += e;
        }
        #pragma unroll
        for (int off = 1; off < 64; off <<= 1) s += __shfl_xor(s, off);
        if (l == 0) ssum[(((g << 3) + r) << 1) + h] = s;
    }
    __syncthreads();

    // Phase C: normalize, gather z_q (h==0 wave writes the full 256-f row), m
    #pragma unroll
    for (int r = 0; r < 8; ++r) {
        const int sidx = ((g << 3) + r) << 1;
        const float rinv = 1.f / (ssum[sidx] + ssum[sidx + 1]);
        #pragma unroll
        for (int t = 0; t < 8; ++t) lg[r][t] *= rinv;
        const int row = row0 + (g << 3) + r;
        if (h == 0) {
            const float4 cv = *(const float4*)(cbk + (size_t)MI[r] * EE + (l << 2));
            *(float4*)(out + (size_t)row * EE + (l << 2)) = cv;
            if (l == 0) out[(size_t)BT * EE + row] = (float)MI[r];
        }
    }

    // avg_p partials: sum p over this thread's 8 rows, LDS-aggregate per col,
    // then one global atomicAdd per column per block.
    #pragma unroll
    for (int t = 0; t < 8; ++t)
        #pragma unroll
        for (int r = 1; r < 8; ++r) lg[0][t] += lg[r][t];
    for (int q = tid; q < KK; q += 512) aggp[q] = 0.f;
    __syncthreads();
    #pragma unroll
    for (int t = 0; t < 8; ++t) {
        const int c = cb0 + ((t >> 2) << 8) + (t & 3);
        atomicAdd(&aggp[c], lg[0][t]);   // 4-way contention (one per row group)
    }
    __syncthreads();
    for (int q = tid; q < KK; q += 512) atomicAdd(&gsum[q], aggp[q]);
}

// Finalize: diversity = sum avg_p * (log(clip(avg_p,1e-9)) + log K); also the
// trailing zero scalar.
__global__ void vq_fin(const float* __restrict__ gsum, float* __restrict__ out) {
    __shared__ float red[4];
    const int tid = threadIdx.x;
    float local = 0.f;
    for (int q = tid; q < KK; q += 256) {
        const float a = gsum[q] * (1.0f / (float)BT);
        local += a * (logf(fmaxf(a, 1e-9f)) + LOGK);
    }
    #pragma unroll
    for (int off = 1; off < 64; off <<= 1) local += __shfl_xor(local, off);
    if ((tid & 63) == 0) red[tid >> 6] = local;
    __syncthreads();
    if (tid == 0) {
        out[(size_t)BT * EE + BT]     = red[0] + red[1] + red[2] + red[3];
        out[(size_t)BT * EE + BT + 1] = 0.f;
    }
}

extern "C" void kernel_launch(void* const* d_in, const int* in_sizes, int n_in,
                              void* d_out, int out_size, void* d_ws, size_t ws_size,
                              hipStream_t stream) {
    const float* x   = (const float*)d_in[0];
    const float* g   = (const float*)d_in[1];
    const float* W   = (const float*)d_in[2];
    const float* b   = (const float*)d_in[3];
    const float* cbk = (const float*)d_in[4];
    float* out  = (float*)d_out;
    float* gsum = (float*)d_ws;

    hipMemsetAsync(gsum, 0, KK * sizeof(float), stream);
    vq_main<<<BT / MT, 512, 0, stream>>>(x, g, W, b, cbk, out, gsum);
    vq_fin<<<1, 256, 0, stream>>>(gsum, out);
}